// Round 7
// baseline (211.918 us; speedup 1.0000x reference)
//
#include <hip/hip_runtime.h>
#include <hip/hip_bf16.h>

typedef unsigned int u32;
typedef unsigned short u16;
using f32x4  = __attribute__((ext_vector_type(4))) float;
using f32x16 = __attribute__((ext_vector_type(16))) float;
using u32x4  = __attribute__((ext_vector_type(4))) u32;
using s16x8  = __attribute__((ext_vector_type(8))) short;

#define DEV static __device__ __forceinline__

DEV u32 pk2(float a, float b) {
  u16 lo = __builtin_bit_cast(u16, __float2bfloat16(a));
  u16 hi = __builtin_bit_cast(u16, __float2bfloat16(b));
  return (u32)lo | ((u32)hi << 16);
}

DEV float bflo(u32 v) { return __builtin_bit_cast(float, v << 16); }
DEV float bfhi(u32 v) { return __builtin_bit_cast(float, v & 0xFFFF0000u); }

DEV f32x16 MFMA32(u32x4 a, u32x4 b, f32x16 c) {
  return __builtin_amdgcn_mfma_f32_32x32x16_bf16(
      __builtin_bit_cast(s16x8, a), __builtin_bit_cast(s16x8, b), c, 0, 0, 0);
}

// swaps upper 32 lanes of a with lower 32 lanes of b
DEV void pl32swap(u32& a, u32& b) {
  asm volatile("v_permlane32_swap_b32 %0, %1" : "+v"(a), "+v"(b));
}

typedef const __attribute__((address_space(1))) u32 gu32;
typedef __attribute__((address_space(3))) u32 lu32;

DEV void load_lds16(const void* g, void* l) {
  __builtin_amdgcn_global_load_lds((gu32*)g, (lu32*)l, 16, 0, 0);
}

// ---------------- pre-kernel 1: per-expert alpha = mean(|W|) ----------------
__global__ void qalpha(const float* __restrict__ w1, const float* __restrict__ w2,
                       float* __restrict__ alphas) {
  int b = blockIdx.x;  // 0..7 -> w1 experts, 8..15 -> w2 experts
  const float* src = (b < 8 ? w1 : w2) + (size_t)(b & 7) * 32768;
  int tid = threadIdx.x;
  float s = 0.f;
  for (int i = tid; i < 32768; i += 256) s += fabsf(src[i]);
  #pragma unroll
  for (int off = 32; off >= 1; off >>= 1) s += __shfl_down(s, off, 64);
  __shared__ float ws4[4];
  if ((tid & 63) == 0) ws4[tid >> 6] = s;
  __syncthreads();
  if (tid == 0) alphas[b] = (ws4[0] + ws4[1] + ws4[2] + ws4[3]) * (1.f / 32768.f);
}

DEV u16 tq1(float v, float thr) {
  return (fabsf(v) > thr) ? (v > 0.f ? (u16)0x3F80 : (u16)0xBF80) : (u16)0;
}
DEV u32 tq2(float a, float b, float thr) {
  return (u32)tq1(a, thr) | ((u32)tq1(b, thr) << 16);
}

// ------- pre-kernel 2: fragment-planar bf16 weight image + bf16 b1 image -------
// chunk n = e*8+ht occupies img[n*16384 .. +16384):
//   w1 plane: img[n*16384 + ks*1024 + l*16]
//     = w1q[e][h = ht*32 + (l&31)][k = ks*16 + (l>>5)*8 + 0..7]  (8 bf16)
//   w2 plane: img[n*16384 + 8192 + (ks2*4+ot)*1024 + l*16]
//     = w2q[e][o = ot*32 + (l&31)][k = ht*32 + ks2*16 + (l>>5)*8 + 0..7]
// b1i[i] (u32, i<1024) = pk2(b1[2i], b1[2i+1])
__global__ void qimg(const float* __restrict__ w1, const float* __restrict__ w2,
                     const float* __restrict__ b1g, const float* __restrict__ alphas,
                     char* __restrict__ img, u32* __restrict__ b1i) {
  int gid = blockIdx.x * 256 + threadIdx.x;  // 66560 total
  if (gid >= 66560) return;
  if (gid >= 65536) {
    int i = gid - 65536;  // 0..1023
    b1i[i] = pk2(b1g[2 * i], b1g[2 * i + 1]);
    return;
  }
  int l = gid & 63;
  int col = l & 31, hi = l >> 5;
  const float* src;
  float thr;
  char* dst;
  if (gid < 32768) {
    int ks = (gid >> 6) & 7;
    int n  = gid >> 9;            // e*8+ht
    int e  = n >> 3, ht = n & 7;
    int h  = ht * 32 + col;
    int k0 = ks * 16 + hi * 8;
    src = w1 + (size_t)e * 32768 + h * 128 + k0;
    thr = 0.5f * alphas[e];
    dst = img + (size_t)n * 16384 + ks * 1024 + l * 16;
  } else {
    int id = gid - 32768;
    int sl = (id >> 6) & 7;       // ks2*4 + ot
    int n  = id >> 9;             // e*8 + c
    int e  = n >> 3, c = n & 7;
    int ks2 = sl >> 2, ot = sl & 3;
    int o  = ot * 32 + col;
    int k0 = c * 32 + ks2 * 16 + hi * 8;
    src = w2 + (size_t)e * 32768 + o * 256 + k0;
    thr = 0.5f * alphas[8 + e];
    dst = img + (size_t)n * 16384 + 8192 + sl * 1024 + l * 16;
  }
  float4 v0 = *(const float4*)src;
  float4 v1 = *(const float4*)(src + 4);
  u32 q0 = tq2(v0.x, v0.y, thr), q1 = tq2(v0.z, v0.w, thr);
  u32 q2 = tq2(v1.x, v1.y, thr), q3 = tq2(v1.z, v1.w, thr);
  *(uint4*)dst = make_uint4(q0, q1, q2, q3);
}

// ---------------- main fused kernel ----------------
// 256 thr = 4 waves x 64 tokens (tt=2), 2 blocks/CU.
// LDS: dbuf 2x32K (chunk-pair) | b1 bf16 4K | gate f32 8K = 76K.
// Iter q (32 iters): vmcnt(0) [drains stage from iter q-1, ~free] -> s_barrier
//   -> stage pair q+1 into buf^1 -> compute chunks 2q, 2q+1 from buf.
#define B1_OFF 65536
#define G_OFF  69632
#define SMEM_BYTES 77824

__global__ __launch_bounds__(256, 2) void moe_main(
    const float* __restrict__ x, const float* __restrict__ b2g,
    const float* __restrict__ wg, const float* __restrict__ bg,
    const char* __restrict__ img, const u32* __restrict__ b1i,
    float* __restrict__ out) {
  extern __shared__ char smem[];
  u32*   s_b1u = (u32*)(smem + B1_OFF);   // [8 e][128] packed bf16 pairs
  float* s_g   = (float*)(smem + G_OFF);  // [8 e][256 t]
  const int tid = threadIdx.x;
  const int w = tid >> 6, l = tid & 63;
  const int col = l & 31, hi = l >> 5;
  const int tokw = blockIdx.x * 256 + w * 64;
  const u32 loff = (u32)(l * 16);

  // stage chunk-pair p (chunks 2p,2p+1; 32KB) into buf p&1; 8KB per wave
  auto stage_pair = [&](int p) {
    const char* src = img + (size_t)p * 32768 + w * 8192 + loff;
    char* dst = smem + (p & 1) * 32768 + w * 8192;
    #pragma unroll
    for (int i = 0; i < 8; ++i)
      load_lds16(src + i * 1024, dst + i * 1024);
  };

  stage_pair(0);  // latency hidden under gate compute

  // ---- b1 bf16 image -> LDS (4KB)
  ((uint4*)s_b1u)[tid] = ((const uint4*)b1i)[tid];

  // ---- xf: x fragments (B operand of GEMM1), bf16, in regs all kernel
  u32x4 xf[2][8];
  #pragma unroll
  for (int tt = 0; tt < 2; ++tt) {
    #pragma unroll
    for (int ks = 0; ks < 8; ++ks) {
      const float* xp = x + (size_t)(tokw + tt * 32 + col) * 128 + ks * 16 + hi * 8;
      float4 v0 = *(const float4*)xp;
      float4 v1 = *(const float4*)(xp + 4);
      xf[tt][ks] = (u32x4){pk2(v0.x, v0.y), pk2(v0.z, v0.w),
                           pk2(v1.x, v1.y), pk2(v1.z, v1.w)};
    }
  }

  // ---- gate: exact f32 logits -> softmax/T -> top-5 -> renorm -> s_g[8][256]
  {
    int t = blockIdx.x * 256 + tid;
    const float4* xr = (const float4*)(x + (size_t)t * 128);
    const float4* wr = (const float4*)wg;
    float lg[8];
    #pragma unroll
    for (int e = 0; e < 8; ++e) lg[e] = bg[e];
    for (int i = 0; i < 32; ++i) {
      float4 xv = xr[i];
      #pragma unroll
      for (int e = 0; e < 8; ++e) {
        float4 wv = wr[e * 32 + i];
        lg[e] += xv.x * wv.x + xv.y * wv.y + xv.z * wv.z + xv.w * wv.w;
      }
    }
    const float invT = 0.36787944117144233f;  // 1/e
    #pragma unroll
    for (int e = 0; e < 8; ++e) lg[e] *= invT;
    float mx = lg[0];
    #pragma unroll
    for (int e = 1; e < 8; ++e) mx = fmaxf(mx, lg[e]);
    float p[8], den = 0.f;
    #pragma unroll
    for (int e = 0; e < 8; ++e) { p[e] = __expf(lg[e] - mx); den += p[e]; }
    float inv = 1.f / den;
    #pragma unroll
    for (int e = 0; e < 8; ++e) p[e] *= inv;
    float gsel[8], wsum = 0.f;
    #pragma unroll
    for (int e = 0; e < 8; ++e) {
      int rank = 0;
      #pragma unroll
      for (int e2 = 0; e2 < 8; ++e2)
        rank += (p[e2] > p[e]) || (p[e2] == p[e] && e2 < e);
      gsel[e] = (rank < 5) ? p[e] : 0.f;
      wsum += gsel[e];
    }
    float r = 1.f / (wsum + 1e-8f);
    #pragma unroll
    for (int e = 0; e < 8; ++e) s_g[e * 256 + tid] = gsel[e] * r;
  }
  __syncthreads();  // gate + b1 visible

  // ---- init acc2[ot][tt] = sum_e g[t][e]*b2[e][o] via one K=16 MFMA pass
  f32x16 acc2[4][2];
  {
    u32x4 gf[2];
    #pragma unroll
    for (int tt = 0; tt < 2; ++tt) {
      u32x4 v = (u32x4){0u, 0u, 0u, 0u};
      if (hi == 0) {
        int t = w * 64 + tt * 32 + col;
        v = (u32x4){pk2(s_g[0 * 256 + t], s_g[1 * 256 + t]),
                    pk2(s_g[2 * 256 + t], s_g[3 * 256 + t]),
                    pk2(s_g[4 * 256 + t], s_g[5 * 256 + t]),
                    pk2(s_g[6 * 256 + t], s_g[7 * 256 + t])};
      }
      gf[tt] = v;
    }
    #pragma unroll
    for (int ot = 0; ot < 4; ++ot) {
      u32x4 af = (u32x4){0u, 0u, 0u, 0u};
      if (hi == 0) {
        int o = ot * 32 + col;
        af = (u32x4){pk2(b2g[0 * 128 + o], b2g[1 * 128 + o]),
                     pk2(b2g[2 * 128 + o], b2g[3 * 128 + o]),
                     pk2(b2g[4 * 128 + o], b2g[5 * 128 + o]),
                     pk2(b2g[6 * 128 + o], b2g[7 * 128 + o])};
      }
      f32x16 z{};
      #pragma unroll
      for (int tt = 0; tt < 2; ++tt) acc2[ot][tt] = MFMA32(af, gf[tt], z);
    }
  }

  // ---- one chunk (tt=2): G1 16 MFMA -> EPI -> G2 16 MFMA
  auto chunk = [&](const char* cb, int e, int ht, float g0, float g1) {
    f32x16 a1_0{}, a1_1{};
    __builtin_amdgcn_s_setprio(1);
    #pragma unroll
    for (int ks = 0; ks < 8; ++ks) {
      u32x4 f = *(const u32x4*)(cb + ks * 1024 + loff);
      a1_0 = MFMA32(f, xf[0][ks], a1_0);
      a1_1 = MFMA32(f, xf[1][ks], a1_1);
    }
    __builtin_amdgcn_s_setprio(0);

    // b1 slice (bf16 -> f32), shared across tt
    float b1v[16];
    #pragma unroll
    for (int rg = 0; rg < 4; ++rg) {
      uint2 bb = *(const uint2*)(s_b1u + e * 128 + ht * 16 + hi * 2 + rg * 4);
      b1v[rg * 4 + 0] = bflo(bb.x);
      b1v[rg * 4 + 1] = bfhi(bb.x);
      b1v[rg * 4 + 2] = bflo(bb.y);
      b1v[rg * 4 + 3] = bfhi(bb.y);
    }

    u32x4 hf[2][2];
    #pragma unroll
    for (int tt = 0; tt < 2; ++tt) {
      const f32x16& a1 = tt ? a1_1 : a1_0;
      const float g = tt ? g1 : g0;
      u32 u[8];
      #pragma unroll
      for (int rg = 0; rg < 4; ++rg) {
        float h0 = fmaxf(a1[rg * 4 + 0] + b1v[rg * 4 + 0], 0.f) * g;
        float h1 = fmaxf(a1[rg * 4 + 1] + b1v[rg * 4 + 1], 0.f) * g;
        float h2 = fmaxf(a1[rg * 4 + 2] + b1v[rg * 4 + 2], 0.f) * g;
        float h3 = fmaxf(a1[rg * 4 + 3] + b1v[rg * 4 + 3], 0.f) * g;
        u[rg * 2 + 0] = pk2(h0, h1);
        u[rg * 2 + 1] = pk2(h2, h3);
      }
      pl32swap(u[0], u[2]);
      pl32swap(u[1], u[3]);
      pl32swap(u[4], u[6]);
      pl32swap(u[5], u[7]);
      hf[0][tt] = (u32x4){u[0], u[1], u[2], u[3]};
      hf[1][tt] = (u32x4){u[4], u[5], u[6], u[7]};
    }

    __builtin_amdgcn_s_setprio(1);
    #pragma unroll
    for (int ks2 = 0; ks2 < 2; ++ks2) {
      #pragma unroll
      for (int ot = 0; ot < 4; ++ot) {
        u32x4 af = *(const u32x4*)(cb + 8192 + (ks2 * 4 + ot) * 1024 + loff);
        acc2[ot][0] = MFMA32(af, hf[ks2][0], acc2[ot][0]);
        acc2[ot][1] = MFMA32(af, hf[ks2][1], acc2[ot][1]);
      }
    }
    __builtin_amdgcn_s_setprio(0);
  };

  // ---- main loop: 32 iters x 2 chunks; 1 barrier + 1 (free) vmcnt(0) per iter
  #pragma unroll 1
  for (int q = 0; q < 32; ++q) {
    asm volatile("s_waitcnt vmcnt(0)" ::: "memory");  // drain stage from q-1
    __builtin_amdgcn_s_barrier();
    __builtin_amdgcn_sched_barrier(0);
    if (q < 31) stage_pair(q + 1);  // issue-early; lands during this compute

    const int e = q >> 2, ht0 = (q & 3) * 2;
    const float g0 = s_g[e * 256 + w * 64 + col];
    const float g1 = s_g[e * 256 + w * 64 + 32 + col];
    const char* buf = smem + (q & 1) * 32768;
    chunk(buf,         e, ht0,     g0, g1);
    chunk(buf + 16384, e, ht0 + 1, g0, g1);
  }

  // ---- store D2[o][t] -> out[t][o]
  #pragma unroll
  for (int ot = 0; ot < 4; ++ot) {
    #pragma unroll
    for (int tt = 0; tt < 2; ++tt) {
      const f32x16& a = acc2[ot][tt];
      float* op = out + (size_t)(tokw + tt * 32 + col) * 128 + ot * 32 + hi * 4;
      #pragma unroll
      for (int rg = 0; rg < 4; ++rg)
        *(f32x4*)(op + rg * 8) =
            (f32x4){a[rg * 4 + 0], a[rg * 4 + 1], a[rg * 4 + 2], a[rg * 4 + 3]};
    }
  }
}

extern "C" void kernel_launch(void* const* d_in, const int* in_sizes, int n_in,
                              void* d_out, int out_size, void* d_ws, size_t ws_size,
                              hipStream_t stream) {
  const float* x  = (const float*)d_in[0];
  const float* w1 = (const float*)d_in[1];
  const float* b1 = (const float*)d_in[2];
  const float* w2 = (const float*)d_in[3];
  const float* b2 = (const float*)d_in[4];
  const float* wg = (const float*)d_in[5];
  const float* bg = (const float*)d_in[6];
  float* out = (float*)d_out;

  if (ws_size < 1052736) return;
  char* ws = (char*)d_ws;
  char* img = ws;                           // 1 MB fragment-planar image
  u32*  b1i = (u32*)(ws + 1048576);         // 4 KB bf16-packed b1
  float* alphas = (float*)(ws + 1052672);   // 16 f32

  int ntok = in_sizes[0] / 128;
  int nblk = ntok / 256;

  qalpha<<<16, 256, 0, stream>>>(w1, w2, alphas);
  qimg<<<260, 256, 0, stream>>>(w1, w2, b1, alphas, img, b1i);

  hipFuncSetAttribute(reinterpret_cast<const void*>(moe_main),
                      hipFuncAttributeMaxDynamicSharedMemorySize, SMEM_BYTES);
  moe_main<<<nblk, 256, SMEM_BYTES, stream>>>(x, b2, wg, bg, img, b1i, out);
}

// Round 8
// 181.232 us; speedup vs baseline: 1.1693x; 1.1693x over previous
//
#include <hip/hip_runtime.h>
#include <hip/hip_bf16.h>

typedef unsigned int u32;
typedef unsigned short u16;
using f32x4  = __attribute__((ext_vector_type(4))) float;
using f32x16 = __attribute__((ext_vector_type(16))) float;
using u32x4  = __attribute__((ext_vector_type(4))) u32;
using s16x8  = __attribute__((ext_vector_type(8))) short;

#define DEV static __device__ __forceinline__

DEV u32 pk2(float a, float b) {
  u16 lo = __builtin_bit_cast(u16, __float2bfloat16(a));
  u16 hi = __builtin_bit_cast(u16, __float2bfloat16(b));
  return (u32)lo | ((u32)hi << 16);
}

DEV f32x16 MFMA32(u32x4 a, u32x4 b, f32x16 c) {
  return __builtin_amdgcn_mfma_f32_32x32x16_bf16(
      __builtin_bit_cast(s16x8, a), __builtin_bit_cast(s16x8, b), c, 0, 0, 0);
}

// swaps upper 32 lanes of a with lower 32 lanes of b
DEV void pl32swap(u32& a, u32& b) {
  asm volatile("v_permlane32_swap_b32 %0, %1" : "+v"(a), "+v"(b));
}

typedef const __attribute__((address_space(1))) u32 gu32;
typedef __attribute__((address_space(3))) u32 lu32;

DEV void load_lds16(const void* g, void* l) {
  __builtin_amdgcn_global_load_lds((gu32*)g, (lu32*)l, 16, 0, 0);
}

// ---------------- pre-kernel 1: per-expert alpha = mean(|W|) ----------------
__global__ void qalpha(const float* __restrict__ w1, const float* __restrict__ w2,
                       float* __restrict__ alphas) {
  int b = blockIdx.x;  // 0..7 -> w1 experts, 8..15 -> w2 experts
  const float* src = (b < 8 ? w1 : w2) + (size_t)(b & 7) * 32768;
  int tid = threadIdx.x;
  float s = 0.f;
  for (int i = tid; i < 32768; i += 256) s += fabsf(src[i]);
  #pragma unroll
  for (int off = 32; off >= 1; off >>= 1) s += __shfl_down(s, off, 64);
  __shared__ float ws4[4];
  if ((tid & 63) == 0) ws4[tid >> 6] = s;
  __syncthreads();
  if (tid == 0) alphas[b] = (ws4[0] + ws4[1] + ws4[2] + ws4[3]) * (1.f / 32768.f);
}

DEV u16 tq1(float v, float thr) {
  return (fabsf(v) > thr) ? (v > 0.f ? (u16)0x3F80 : (u16)0xBF80) : (u16)0;
}
DEV u32 tq2(float a, float b, float thr) {
  return (u32)tq1(a, thr) | ((u32)tq1(b, thr) << 16);
}

// ------- pre-kernel 2: fragment-planar bf16 weight image (coalesced loads) -------
// chunk n = e*8+ht occupies img[n*16384 .. +16384):
//   w1 plane: img[n*16384 + ks*1024 + l*16]
//     = w1q[e][h = ht*32 + (l&31)][k = ks*16 + (l>>5)*8 + 0..7]  (8 bf16)
//   w2 plane: img[n*16384 + 8192 + (ks2*4+ot)*1024 + l*16]
//     = w2q[e][o = ot*32 + (l&31)][k = ht*32 + ks2*16 + (l>>5)*8 + 0..7]
__global__ void qimg(const float* __restrict__ w1, const float* __restrict__ w2,
                     const float* __restrict__ alphas, char* __restrict__ img) {
  int gid = blockIdx.x * 256 + threadIdx.x;  // 65536 total
  int l = gid & 63;
  int col = l & 31, hi = l >> 5;
  const float* src;
  float thr;
  char* dst;
  if (gid < 32768) {
    int ks = (gid >> 6) & 7;
    int n  = gid >> 9;            // e*8+ht
    int e  = n >> 3, ht = n & 7;
    int h  = ht * 32 + col;
    int k0 = ks * 16 + hi * 8;
    src = w1 + (size_t)e * 32768 + h * 128 + k0;
    thr = 0.5f * alphas[e];
    dst = img + (size_t)n * 16384 + ks * 1024 + l * 16;
  } else {
    int id = gid - 32768;
    int sl = (id >> 6) & 7;       // ks2*4 + ot
    int n  = id >> 9;             // e*8 + c
    int e  = n >> 3, c = n & 7;
    int ks2 = sl >> 2, ot = sl & 3;
    int o  = ot * 32 + col;
    int k0 = c * 32 + ks2 * 16 + hi * 8;
    src = w2 + (size_t)e * 32768 + o * 256 + k0;
    thr = 0.5f * alphas[8 + e];
    dst = img + (size_t)n * 16384 + 8192 + sl * 1024 + l * 16;
  }
  float4 v0 = *(const float4*)src;
  float4 v1 = *(const float4*)(src + 4);
  u32 q0 = tq2(v0.x, v0.y, thr), q1 = tq2(v0.z, v0.w, thr);
  u32 q2 = tq2(v1.x, v1.y, thr), q3 = tq2(v1.z, v1.w, thr);
  *(uint4*)dst = make_uint4(q0, q1, q2, q3);
}

// ---------------- main fused kernel ----------------
// 256 thr = 4 waves x 64 tokens (tt=2), 2 blocks/CU.
// LDS: dbuf 2x32K (chunk-pair) | b1 f32 8K | gate f32 8K = 80K (2 blocks = 160K).
// Iter q (32 iters): vmcnt(0) [drains stage issued in iter q-1, ~free] ->
//   s_barrier -> issue stage pair q+1 -> compute chunk 2q -> sched fence ->
//   compute chunk 2q+1. One barrier per 64 MFMA/wave.
#define B1_OFF 65536
#define G_OFF  73728
#define SMEM_BYTES 81920

__global__ __launch_bounds__(256, 2) void moe_main(
    const float* __restrict__ x, const float* __restrict__ b1g,
    const float* __restrict__ b2g, const float* __restrict__ wg,
    const float* __restrict__ bg, const char* __restrict__ img,
    float* __restrict__ out) {
  extern __shared__ char smem[];
  float* s_b1 = (float*)(smem + B1_OFF);  // [8 e][256 h] f32
  float* s_g  = (float*)(smem + G_OFF);   // [8 e][256 t] f32
  const int tid = threadIdx.x;
  const int w = tid >> 6, l = tid & 63;
  const int col = l & 31, hi = l >> 5;
  const int tokw = blockIdx.x * 256 + w * 64;
  const u32 loff = (u32)(l * 16);

  // stage chunk-pair p (chunks 2p,2p+1; 32KB) into buf p&1; 8KB per wave
  auto stage_pair = [&](int p) {
    const char* src = img + (size_t)p * 32768 + w * 8192 + loff;
    char* dst = smem + (p & 1) * 32768 + w * 8192;
    #pragma unroll
    for (int i = 0; i < 8; ++i)
      load_lds16(src + i * 1024, dst + i * 1024);
  };

  stage_pair(0);  // latency hidden under gate compute

  // ---- b1 f32 -> LDS (8KB), plain copy (covered by gate barrier)
  {
    const float4* s = (const float4*)b1g;
    float4* d = (float4*)s_b1;
    d[tid] = s[tid];
    d[tid + 256] = s[tid + 256];
  }

  // ---- xf: x fragments (B operand of GEMM1), bf16, in regs all kernel
  u32x4 xf[2][8];
  #pragma unroll
  for (int tt = 0; tt < 2; ++tt) {
    #pragma unroll
    for (int ks = 0; ks < 8; ++ks) {
      const float* xp = x + (size_t)(tokw + tt * 32 + col) * 128 + ks * 16 + hi * 8;
      float4 v0 = *(const float4*)xp;
      float4 v1 = *(const float4*)(xp + 4);
      xf[tt][ks] = (u32x4){pk2(v0.x, v0.y), pk2(v0.z, v0.w),
                           pk2(v1.x, v1.y), pk2(v1.z, v1.w)};
    }
  }

  // ---- gate: exact f32 logits -> softmax/T -> top-5 -> renorm -> s_g[8][256]
  {
    int t = blockIdx.x * 256 + tid;
    const float4* xr = (const float4*)(x + (size_t)t * 128);
    const float4* wr = (const float4*)wg;
    float lg[8];
    #pragma unroll
    for (int e = 0; e < 8; ++e) lg[e] = bg[e];
    for (int i = 0; i < 32; ++i) {
      float4 xv = xr[i];
      #pragma unroll
      for (int e = 0; e < 8; ++e) {
        float4 wv = wr[e * 32 + i];
        lg[e] += xv.x * wv.x + xv.y * wv.y + xv.z * wv.z + xv.w * wv.w;
      }
    }
    const float invT = 0.36787944117144233f;  // 1/e
    #pragma unroll
    for (int e = 0; e < 8; ++e) lg[e] *= invT;
    float mx = lg[0];
    #pragma unroll
    for (int e = 1; e < 8; ++e) mx = fmaxf(mx, lg[e]);
    float p[8], den = 0.f;
    #pragma unroll
    for (int e = 0; e < 8; ++e) { p[e] = __expf(lg[e] - mx); den += p[e]; }
    float inv = 1.f / den;
    #pragma unroll
    for (int e = 0; e < 8; ++e) p[e] *= inv;
    float gsel[8], wsum = 0.f;
    #pragma unroll
    for (int e = 0; e < 8; ++e) {
      int rank = 0;
      #pragma unroll
      for (int e2 = 0; e2 < 8; ++e2)
        rank += (p[e2] > p[e]) || (p[e2] == p[e] && e2 < e);
      gsel[e] = (rank < 5) ? p[e] : 0.f;
      wsum += gsel[e];
    }
    float r = 1.f / (wsum + 1e-8f);
    #pragma unroll
    for (int e = 0; e < 8; ++e) s_g[e * 256 + tid] = gsel[e] * r;
  }
  __syncthreads();  // gate + b1 visible; drains prologue staging

  // ---- init acc2[ot][tt] = sum_e g[t][e]*b2[e][o] via one K=16 MFMA pass
  f32x16 acc2[4][2];
  {
    u32x4 gf[2];
    #pragma unroll
    for (int tt = 0; tt < 2; ++tt) {
      u32x4 v = (u32x4){0u, 0u, 0u, 0u};
      if (hi == 0) {
        int t = w * 64 + tt * 32 + col;
        v = (u32x4){pk2(s_g[0 * 256 + t], s_g[1 * 256 + t]),
                    pk2(s_g[2 * 256 + t], s_g[3 * 256 + t]),
                    pk2(s_g[4 * 256 + t], s_g[5 * 256 + t]),
                    pk2(s_g[6 * 256 + t], s_g[7 * 256 + t])};
      }
      gf[tt] = v;
    }
    #pragma unroll
    for (int ot = 0; ot < 4; ++ot) {
      u32x4 af = (u32x4){0u, 0u, 0u, 0u};
      if (hi == 0) {
        int o = ot * 32 + col;
        af = (u32x4){pk2(b2g[0 * 128 + o], b2g[1 * 128 + o]),
                     pk2(b2g[2 * 128 + o], b2g[3 * 128 + o]),
                     pk2(b2g[4 * 128 + o], b2g[5 * 128 + o]),
                     pk2(b2g[6 * 128 + o], b2g[7 * 128 + o])};
      }
      f32x16 z{};
      #pragma unroll
      for (int tt = 0; tt < 2; ++tt) acc2[ot][tt] = MFMA32(af, gf[tt], z);
    }
  }

  // ---- one chunk (tt=2): G1 16 MFMA -> EPI -> G2 16 MFMA (v3-proven layout)
  auto chunk = [&](const char* cb, int e, int ht, float g0, float g1) {
    f32x16 a1_0{}, a1_1{};
    __builtin_amdgcn_s_setprio(1);
    #pragma unroll
    for (int ks = 0; ks < 8; ++ks) {
      u32x4 f = *(const u32x4*)(cb + ks * 1024 + loff);
      a1_0 = MFMA32(f, xf[0][ks], a1_0);
      a1_1 = MFMA32(f, xf[1][ks], a1_1);
    }
    __builtin_amdgcn_s_setprio(0);

    const float* b1b = s_b1 + e * 256 + ht * 32 + hi * 4;
    u32x4 hf[2][2];
    #pragma unroll
    for (int tt = 0; tt < 2; ++tt) {
      const f32x16& a1 = tt ? a1_1 : a1_0;
      const float g = tt ? g1 : g0;
      u32 u[8];
      #pragma unroll
      for (int rg = 0; rg < 4; ++rg) {
        f32x4 bb = *(const f32x4*)(b1b + rg * 8);
        float h0 = fmaxf(a1[rg * 4 + 0] + bb.x, 0.f) * g;
        float h1 = fmaxf(a1[rg * 4 + 1] + bb.y, 0.f) * g;
        float h2 = fmaxf(a1[rg * 4 + 2] + bb.z, 0.f) * g;
        float h3 = fmaxf(a1[rg * 4 + 3] + bb.w, 0.f) * g;
        u[rg * 2 + 0] = pk2(h0, h1);
        u[rg * 2 + 1] = pk2(h2, h3);
      }
      pl32swap(u[0], u[2]);
      pl32swap(u[1], u[3]);
      pl32swap(u[4], u[6]);
      pl32swap(u[5], u[7]);
      hf[0][tt] = (u32x4){u[0], u[1], u[2], u[3]};
      hf[1][tt] = (u32x4){u[4], u[5], u[6], u[7]};
    }

    __builtin_amdgcn_s_setprio(1);
    #pragma unroll
    for (int ks2 = 0; ks2 < 2; ++ks2) {
      #pragma unroll
      for (int ot = 0; ot < 4; ++ot) {
        u32x4 af = *(const u32x4*)(cb + 8192 + (ks2 * 4 + ot) * 1024 + loff);
        acc2[ot][0] = MFMA32(af, hf[ks2][0], acc2[ot][0]);
        acc2[ot][1] = MFMA32(af, hf[ks2][1], acc2[ot][1]);
      }
    }
    __builtin_amdgcn_s_setprio(0);
  };

  // ---- main loop: 32 iters x 2 chunks; 1 barrier + 1 (cheap) vmcnt(0) per iter
  #pragma unroll 1
  for (int q = 0; q < 32; ++q) {
    asm volatile("s_waitcnt vmcnt(0)" ::: "memory");  // stage from q-1: landed
    __builtin_amdgcn_s_barrier();
    __builtin_amdgcn_sched_barrier(0);
    if (q < 31) stage_pair(q + 1);  // issue-early; lands during this compute

    const int e = q >> 2, ht0 = (q & 3) * 2;
    const float g0 = s_g[e * 256 + w * 64 + col];
    const float g1 = s_g[e * 256 + w * 64 + 32 + col];
    const char* buf = smem + (q & 1) * 32768;
    chunk(buf, e, ht0, g0, g1);
    __builtin_amdgcn_sched_barrier(0);  // fence: no cross-chunk frag hoisting
    chunk(buf + 16384, e, ht0 + 1, g0, g1);
  }

  // ---- store D2[o][t] -> out[t][o]
  #pragma unroll
  for (int ot = 0; ot < 4; ++ot) {
    #pragma unroll
    for (int tt = 0; tt < 2; ++tt) {
      const f32x16& a = acc2[ot][tt];
      float* op = out + (size_t)(tokw + tt * 32 + col) * 128 + ot * 32 + hi * 4;
      #pragma unroll
      for (int rg = 0; rg < 4; ++rg)
        *(f32x4*)(op + rg * 8) =
            (f32x4){a[rg * 4 + 0], a[rg * 4 + 1], a[rg * 4 + 2], a[rg * 4 + 3]};
    }
  }
}

extern "C" void kernel_launch(void* const* d_in, const int* in_sizes, int n_in,
                              void* d_out, int out_size, void* d_ws, size_t ws_size,
                              hipStream_t stream) {
  const float* x  = (const float*)d_in[0];
  const float* w1 = (const float*)d_in[1];
  const float* b1 = (const float*)d_in[2];
  const float* w2 = (const float*)d_in[3];
  const float* b2 = (const float*)d_in[4];
  const float* wg = (const float*)d_in[5];
  const float* bg = (const float*)d_in[6];
  float* out = (float*)d_out;

  if (ws_size < 1048640) return;
  char* ws = (char*)d_ws;
  char* img = ws;                          // 1 MB fragment-planar image
  float* alphas = (float*)(ws + 1048576);  // 16 f32

  int ntok = in_sizes[0] / 128;
  int nblk = ntok / 256;

  qalpha<<<16, 256, 0, stream>>>(w1, w2, alphas);
  qimg<<<256, 256, 0, stream>>>(w1, w2, alphas, img);

  hipFuncSetAttribute(reinterpret_cast<const void*>(moe_main),
                      hipFuncAttributeMaxDynamicSharedMemorySize, SMEM_BYTES);
  moe_main<<<nblk, 256, SMEM_BYTES, stream>>>(x, b1, b2, wg, bg, img, out);
}